// Round 1
// baseline (504.531 us; speedup 1.0000x reference)
//
#include <hip/hip_runtime.h>

#define D_IN 256
#define D_OUT 128
#define ALPHA 0.2f

#define BM 32
#define BK 64
#define SCAN_CHUNK 2048

// ---------------- GEMM: h = x @ W  (fp32, 4x4 register tile) ----------------
__global__ __launch_bounds__(256) void k_gemm(const float* __restrict__ x,
                                              const float* __restrict__ W,
                                              float* __restrict__ h, int n) {
    __shared__ float sXT[BK][BM + 4];   // x tile transposed, padded for banks/alignment
    __shared__ float sW[BK][D_OUT];
    const int t = threadIdx.x;
    const int tx = t & 31;          // col group (4 cols each)
    const int ty = t >> 5;          // row group (4 rows each)
    const int row0 = blockIdx.x * BM;

    float acc[4][4] = {};

    for (int k0 = 0; k0 < D_IN; k0 += BK) {
        // load x tile (transposed into LDS), coalesced on global
        for (int i = t; i < BM * BK; i += 256) {
            int c = i & (BK - 1);
            int r = i >> 6;
            int gr = row0 + r;
            sXT[c][r] = (gr < n) ? x[(size_t)gr * D_IN + k0 + c] : 0.f;
        }
        // load W tile, coalesced
        for (int i = t; i < BK * D_OUT; i += 256) {
            int c = i & (D_OUT - 1);
            int r = i >> 7;
            sW[r][c] = W[(size_t)(k0 + r) * D_OUT + c];
        }
        __syncthreads();
        #pragma unroll 8
        for (int k = 0; k < BK; ++k) {
            float4 xv = *(const float4*)&sXT[k][ty * 4];
            float4 wv = *(const float4*)&sW[k][tx * 4];
            float xr[4] = {xv.x, xv.y, xv.z, xv.w};
            float wr[4] = {wv.x, wv.y, wv.z, wv.w};
            #pragma unroll
            for (int r = 0; r < 4; ++r)
                #pragma unroll
                for (int c = 0; c < 4; ++c)
                    acc[r][c] = fmaf(xr[r], wr[c], acc[r][c]);
        }
        __syncthreads();
    }
    #pragma unroll
    for (int r = 0; r < 4; ++r) {
        int gr = row0 + ty * 4 + r;
        if (gr < n) {
            float4 o = make_float4(acc[r][0], acc[r][1], acc[r][2], acc[r][3]);
            *(float4*)&h[(size_t)gr * D_OUT + tx * 4] = o;
        }
    }
}

// ---------------- f_src / f_dst : per-node projections ----------------
__global__ __launch_bounds__(256) void k_f(const float* __restrict__ h,
                                           const float* __restrict__ a,
                                           float* __restrict__ f_src,
                                           float* __restrict__ f_dst, int n) {
    const int node = blockIdx.x * 4 + (threadIdx.x >> 6);
    const int lane = threadIdx.x & 63;
    if (node >= n) return;
    float2 hv = *(const float2*)&h[(size_t)node * D_OUT + lane * 2];
    float fs = hv.x * a[lane * 2]           + hv.y * a[lane * 2 + 1];
    float fd = hv.x * a[D_OUT + lane * 2]   + hv.y * a[D_OUT + lane * 2 + 1];
    #pragma unroll
    for (int off = 32; off > 0; off >>= 1) {
        fs += __shfl_down(fs, off);
        fd += __shfl_down(fd, off);
    }
    if (lane == 0) {
        f_src[node] = fs;
        f_dst[node] = fd;
    }
}

// ---------------- histogram of src ----------------
__global__ __launch_bounds__(256) void k_hist(const int* __restrict__ src,
                                              int* __restrict__ counts, int E) {
    for (int e = blockIdx.x * blockDim.x + threadIdx.x; e < E;
         e += gridDim.x * blockDim.x) {
        atomicAdd(&counts[src[e]], 1);
    }
}

// ---------------- scan pass 1: per-block totals ----------------
__global__ __launch_bounds__(256) void k_scan1(const int* __restrict__ counts,
                                               int* __restrict__ block_sums, int n) {
    const int t = threadIdx.x;
    const int base = blockIdx.x * SCAN_CHUNK;
    int s = 0;
    for (int i = t; i < SCAN_CHUNK; i += 256) {
        int idx = base + i;
        if (idx < n) s += counts[idx];
    }
    #pragma unroll
    for (int off = 32; off > 0; off >>= 1) s += __shfl_down(s, off);
    __shared__ int wsums[4];
    if ((t & 63) == 0) wsums[t >> 6] = s;
    __syncthreads();
    if (t == 0) block_sums[blockIdx.x] = wsums[0] + wsums[1] + wsums[2] + wsums[3];
}

// ---------------- scan pass 2: full exclusive scan, writes row_ptr & cursor ----------------
__global__ __launch_bounds__(256) void k_scan2(const int* __restrict__ counts,
                                               const int* __restrict__ block_sums,
                                               int* __restrict__ row_ptr,
                                               int* __restrict__ cursor, int n) {
    const int t = threadIdx.x;
    const int b = blockIdx.x;
    const int base = b * SCAN_CHUNK;

    // offset = sum of previous block totals
    int po = 0;
    for (int i = t; i < b; i += 256) po += block_sums[i];
    #pragma unroll
    for (int off = 32; off > 0; off >>= 1) po += __shfl_down(po, off);
    __shared__ int wsums[4];
    __shared__ int sOff;
    if ((t & 63) == 0) wsums[t >> 6] = po;
    __syncthreads();
    if (t == 0) sOff = wsums[0] + wsums[1] + wsums[2] + wsums[3];
    __syncthreads();

    // each thread scans 8 consecutive elements
    const int idx0 = base + t * 8;
    int v[8];
    int total = 0;
    #pragma unroll
    for (int j = 0; j < 8; ++j) {
        int idx = idx0 + j;
        v[j] = (idx < n) ? counts[idx] : 0;
        total += v[j];
    }
    // block scan of per-thread totals (Hillis-Steele, inclusive)
    __shared__ int sc[256];
    sc[t] = total;
    __syncthreads();
    #pragma unroll
    for (int off = 1; off < 256; off <<= 1) {
        int add = (t >= off) ? sc[t - off] : 0;
        __syncthreads();
        sc[t] += add;
        __syncthreads();
    }
    int gbase = sOff + sc[t] - total;   // exclusive base for this thread
    int run = 0;
    #pragma unroll
    for (int j = 0; j < 8; ++j) {
        int idx = idx0 + j;
        if (idx < n) {
            row_ptr[idx] = gbase + run;
            cursor[idx]  = gbase + run;
        }
        run += v[j];
    }
}

// ---------------- CSR fill ----------------
__global__ __launch_bounds__(256) void k_fill(const int* __restrict__ src,
                                              const int* __restrict__ dst,
                                              int* __restrict__ cursor,
                                              int* __restrict__ csr_dst, int E) {
    for (int e = blockIdx.x * blockDim.x + threadIdx.x; e < E;
         e += gridDim.x * blockDim.x) {
        int s = src[e];
        int p = atomicAdd(&cursor[s], 1);
        csr_dst[p] = dst[e];
    }
}

// ---------------- aggregation: one wave per src node ----------------
__global__ __launch_bounds__(256) void k_agg(const float* __restrict__ h,
                                             const float* __restrict__ f_src,
                                             const float* __restrict__ f_dst,
                                             const int* __restrict__ row_ptr,
                                             const int* __restrict__ csr_dst,
                                             float* __restrict__ out, int n, int E) {
    const int node = blockIdx.x * 4 + (threadIdx.x >> 6);
    if (node >= n) return;
    const int lane = threadIdx.x & 63;
    const int beg = row_ptr[node];
    const int end = (node == n - 1) ? E : row_ptr[node + 1];
    const float fs = f_src[node];

    float acc0 = 0.f, acc1 = 0.f, rowsum = 0.f;
    for (int j = beg; j < end; ++j) {
        int d = csr_dst[j];
        float tmp = fs + f_dst[d];
        float l = (tmp > 0.f) ? tmp : ALPHA * tmp;
        float e = __expf(-l);
        rowsum += e;
        float2 hv = *(const float2*)&h[(size_t)d * D_OUT + lane * 2];
        acc0 = fmaf(e, hv.x, acc0);
        acc1 = fmaf(e, hv.y, acc1);
    }
    float inv = 1.f / rowsum;
    acc0 *= inv;
    acc1 *= inv;
    // ELU
    acc0 = (acc0 > 0.f) ? acc0 : (__expf(acc0) - 1.f);
    acc1 = (acc1 > 0.f) ? acc1 : (__expf(acc1) - 1.f);
    *(float2*)&out[(size_t)node * D_OUT + lane * 2] = make_float2(acc0, acc1);
}

extern "C" void kernel_launch(void* const* d_in, const int* in_sizes, int n_in,
                              void* d_out, int out_size, void* d_ws, size_t ws_size,
                              hipStream_t stream) {
    const float* x    = (const float*)d_in[0];
    const int*   edge = (const int*)d_in[1];   // JAX no-x64: int64 -> int32
    const float* W    = (const float*)d_in[2];
    const float* a    = (const float*)d_in[3];
    float* out = (float*)d_out;

    const int n = in_sizes[0] / D_IN;
    const int E = in_sizes[1] / 2;
    const int* src = edge;
    const int* dst = edge + E;

    // workspace layout
    char* p = (char*)d_ws;
    float* h       = (float*)p;  p += (size_t)n * D_OUT * sizeof(float);
    float* f_src   = (float*)p;  p += (size_t)n * sizeof(float);
    float* f_dst   = (float*)p;  p += (size_t)n * sizeof(float);
    int*   counts  = (int*)p;    p += (size_t)n * sizeof(int);
    int*   row_ptr = (int*)p;    p += (size_t)(n + 1) * sizeof(int);
    int*   cursor  = (int*)p;    p += (size_t)n * sizeof(int);
    int*   csr_dst = (int*)p;    p += (size_t)E * sizeof(int);
    int*   block_sums = (int*)p; p += 64 * sizeof(int);

    const int gemm_blocks = (n + BM - 1) / BM;
    const int scan_blocks = (n + SCAN_CHUNK - 1) / SCAN_CHUNK;

    k_gemm<<<gemm_blocks, 256, 0, stream>>>(x, W, h, n);
    k_f<<<(n + 3) / 4, 256, 0, stream>>>(h, a, f_src, f_dst, n);

    hipMemsetAsync(counts, 0, (size_t)n * sizeof(int), stream);
    k_hist<<<1280, 256, 0, stream>>>(src, counts, E);
    k_scan1<<<scan_blocks, 256, 0, stream>>>(counts, block_sums, n);
    k_scan2<<<scan_blocks, 256, 0, stream>>>(counts, block_sums, row_ptr, cursor, n);
    k_fill<<<1280, 256, 0, stream>>>(src, dst, cursor, csr_dst, E);

    k_agg<<<(n + 3) / 4, 256, 0, stream>>>(h, f_src, f_dst, row_ptr, csr_dst, out, n, E);
}

// Round 2
// 436.033 us; speedup vs baseline: 1.1571x; 1.1571x over previous
//
#include <hip/hip_runtime.h>

#define D_IN 256
#define D_OUT 128
#define ALPHA 0.2f
#define SCAN_CHUNK 2048

typedef __attribute__((ext_vector_type(8))) short bf16x8;
typedef __attribute__((ext_vector_type(4))) float f32x4;
typedef __attribute__((ext_vector_type(8))) unsigned short us8;

__device__ inline unsigned short f2bf(float f) {
    unsigned int u = __float_as_uint(f);
    return (unsigned short)((u + 0x7FFFu + ((u >> 16) & 1u)) >> 16);
}
__device__ inline float bf2f(unsigned short u) {
    return __uint_as_float(((unsigned int)u) << 16);
}

// ---------------- W [256][128] fp32 -> WTb [128][256] bf16 (transposed) ----------------
__global__ __launch_bounds__(256) void k_wt(const float* __restrict__ W,
                                            unsigned short* __restrict__ WTb) {
    const int ncol = blockIdx.x;     // 0..127
    const int k = threadIdx.x;       // 0..255
    WTb[(size_t)ncol * 256 + k] = f2bf(W[(size_t)k * 128 + ncol]);
}

// ---------------- GEMM: hb = bf16(x) @ W, MFMA 16x16x32, no LDS ----------------
// block = 128 rows x 128 cols, 4 waves in 2x2, each wave 64x64 (4x4 fragments)
__global__ __launch_bounds__(256) void k_gemm(const float* __restrict__ x,
                                              const unsigned short* __restrict__ WTb,
                                              unsigned short* __restrict__ hb, int n) {
    const int t = threadIdx.x;
    const int l = t & 63;
    const int w = t >> 6;
    const int wr = w >> 1, wc = w & 1;
    const int row0 = blockIdx.x * 128 + wr * 64;
    const int col0 = wc * 64;
    const int lr = l & 15;           // row (A) / col (B) within fragment
    const int lk = (l >> 4) * 8;     // k offset within 32-wide K step

    f32x4 acc[4][4] = {};

    const float* ap[4];
    #pragma unroll
    for (int mi = 0; mi < 4; ++mi) {
        int r = row0 + mi * 16 + lr;
        if (r > n - 1) r = n - 1;    // clamp; stores are masked
        ap[mi] = x + (size_t)r * D_IN + lk;
    }
    const unsigned short* bp[4];
    #pragma unroll
    for (int ni = 0; ni < 4; ++ni)
        bp[ni] = WTb + (size_t)(col0 + ni * 16 + lr) * 256 + lk;

    #pragma unroll
    for (int k0 = 0; k0 < D_IN; k0 += 32) {
        bf16x8 af[4], bfr[4];
        #pragma unroll
        for (int mi = 0; mi < 4; ++mi) {
            float4 fa = *(const float4*)(ap[mi] + k0);
            float4 fb = *(const float4*)(ap[mi] + k0 + 4);
            bf16x8 v;
            v[0] = (short)f2bf(fa.x); v[1] = (short)f2bf(fa.y);
            v[2] = (short)f2bf(fa.z); v[3] = (short)f2bf(fa.w);
            v[4] = (short)f2bf(fb.x); v[5] = (short)f2bf(fb.y);
            v[6] = (short)f2bf(fb.z); v[7] = (short)f2bf(fb.w);
            af[mi] = v;
        }
        #pragma unroll
        for (int ni = 0; ni < 4; ++ni)
            bfr[ni] = *(const bf16x8*)(bp[ni] + k0);
        #pragma unroll
        for (int mi = 0; mi < 4; ++mi)
            #pragma unroll
            for (int ni = 0; ni < 4; ++ni)
                acc[mi][ni] = __builtin_amdgcn_mfma_f32_16x16x32_bf16(
                    af[mi], bfr[ni], acc[mi][ni], 0, 0, 0);
    }

    // C/D layout: col = lane&15, row = (lane>>4)*4 + q   [m89/m91 verified]
    const int rq = (l >> 4) * 4;
    #pragma unroll
    for (int mi = 0; mi < 4; ++mi) {
        #pragma unroll
        for (int q = 0; q < 4; ++q) {
            int r = row0 + mi * 16 + rq + q;
            if (r < n) {
                #pragma unroll
                for (int ni = 0; ni < 4; ++ni)
                    hb[(size_t)r * D_OUT + col0 + ni * 16 + lr] =
                        f2bf(acc[mi][ni][q]);
            }
        }
    }
}

// ---------------- f_src / f_dst : per-node projections (bf16 h) ----------------
__global__ __launch_bounds__(256) void k_f(const unsigned short* __restrict__ hb,
                                           const float* __restrict__ a,
                                           float* __restrict__ f_src,
                                           float* __restrict__ f_dst, int n) {
    const int node = blockIdx.x * 4 + (threadIdx.x >> 6);
    const int lane = threadIdx.x & 63;
    if (node >= n) return;
    ushort2 hv = *(const ushort2*)&hb[(size_t)node * D_OUT + lane * 2];
    float h0 = bf2f(hv.x), h1 = bf2f(hv.y);
    float fs = h0 * a[lane * 2]         + h1 * a[lane * 2 + 1];
    float fd = h0 * a[D_OUT + lane * 2] + h1 * a[D_OUT + lane * 2 + 1];
    #pragma unroll
    for (int off = 32; off > 0; off >>= 1) {
        fs += __shfl_down(fs, off);
        fd += __shfl_down(fd, off);
    }
    if (lane == 0) {
        f_src[node] = fs;
        f_dst[node] = fd;
    }
}

// ---------------- histogram of src ----------------
__global__ __launch_bounds__(256) void k_hist(const int* __restrict__ src,
                                              int* __restrict__ counts, int E) {
    for (int e = blockIdx.x * blockDim.x + threadIdx.x; e < E;
         e += gridDim.x * blockDim.x) {
        atomicAdd(&counts[src[e]], 1);
    }
}

// ---------------- scan pass 1: per-block totals ----------------
__global__ __launch_bounds__(256) void k_scan1(const int* __restrict__ counts,
                                               int* __restrict__ block_sums, int n) {
    const int t = threadIdx.x;
    const int base = blockIdx.x * SCAN_CHUNK;
    int s = 0;
    for (int i = t; i < SCAN_CHUNK; i += 256) {
        int idx = base + i;
        if (idx < n) s += counts[idx];
    }
    #pragma unroll
    for (int off = 32; off > 0; off >>= 1) s += __shfl_down(s, off);
    __shared__ int wsums[4];
    if ((t & 63) == 0) wsums[t >> 6] = s;
    __syncthreads();
    if (t == 0) block_sums[blockIdx.x] = wsums[0] + wsums[1] + wsums[2] + wsums[3];
}

// ---------------- scan pass 2: exclusive scan -> row_ptr & cursor ----------------
__global__ __launch_bounds__(256) void k_scan2(const int* __restrict__ counts,
                                               const int* __restrict__ block_sums,
                                               int* __restrict__ row_ptr,
                                               int* __restrict__ cursor, int n) {
    const int t = threadIdx.x;
    const int b = blockIdx.x;
    const int base = b * SCAN_CHUNK;

    int po = 0;
    for (int i = t; i < b; i += 256) po += block_sums[i];
    #pragma unroll
    for (int off = 32; off > 0; off >>= 1) po += __shfl_down(po, off);
    __shared__ int wsums[4];
    __shared__ int sOff;
    if ((t & 63) == 0) wsums[t >> 6] = po;
    __syncthreads();
    if (t == 0) sOff = wsums[0] + wsums[1] + wsums[2] + wsums[3];
    __syncthreads();

    const int idx0 = base + t * 8;
    int v[8];
    int total = 0;
    #pragma unroll
    for (int j = 0; j < 8; ++j) {
        int idx = idx0 + j;
        v[j] = (idx < n) ? counts[idx] : 0;
        total += v[j];
    }
    __shared__ int sc[256];
    sc[t] = total;
    __syncthreads();
    #pragma unroll
    for (int off = 1; off < 256; off <<= 1) {
        int add = (t >= off) ? sc[t - off] : 0;
        __syncthreads();
        sc[t] += add;
        __syncthreads();
    }
    int gbase = sOff + sc[t] - total;
    int run = 0;
    #pragma unroll
    for (int j = 0; j < 8; ++j) {
        int idx = idx0 + j;
        if (idx < n) {
            row_ptr[idx] = gbase + run;
            cursor[idx]  = gbase + run;
        }
        run += v[j];
    }
}

// ---------------- CSR fill ----------------
__global__ __launch_bounds__(256) void k_fill(const int* __restrict__ src,
                                              const int* __restrict__ dst,
                                              int* __restrict__ cursor,
                                              int* __restrict__ csr_dst, int E) {
    for (int e = blockIdx.x * blockDim.x + threadIdx.x; e < E;
         e += gridDim.x * blockDim.x) {
        int s = src[e];
        int p = atomicAdd(&cursor[s], 1);
        csr_dst[p] = dst[e];
    }
}

// ---------------- aggregation: one wave per src node, bf16 h gather ----------------
__global__ __launch_bounds__(256) void k_agg(const unsigned short* __restrict__ hb,
                                             const float* __restrict__ f_src,
                                             const float* __restrict__ f_dst,
                                             const int* __restrict__ row_ptr,
                                             const int* __restrict__ csr_dst,
                                             float* __restrict__ out, int n, int E) {
    const int node = blockIdx.x * 4 + (threadIdx.x >> 6);
    if (node >= n) return;
    const int lane = threadIdx.x & 63;
    const int beg = row_ptr[node];
    const int end = (node == n - 1) ? E : row_ptr[node + 1];
    const float fs = f_src[node];

    float acc0 = 0.f, acc1 = 0.f, rowsum = 0.f;
    for (int j = beg; j < end; ++j) {
        int d = csr_dst[j];
        float tmp = fs + f_dst[d];
        float lr = (tmp > 0.f) ? tmp : ALPHA * tmp;
        float e = __expf(-lr);
        rowsum += e;
        ushort2 hv = *(const ushort2*)&hb[(size_t)d * D_OUT + lane * 2];
        acc0 = fmaf(e, bf2f(hv.x), acc0);
        acc1 = fmaf(e, bf2f(hv.y), acc1);
    }
    float inv = 1.f / rowsum;
    acc0 *= inv;
    acc1 *= inv;
    acc0 = (acc0 > 0.f) ? acc0 : (__expf(acc0) - 1.f);
    acc1 = (acc1 > 0.f) ? acc1 : (__expf(acc1) - 1.f);
    *(float2*)&out[(size_t)node * D_OUT + lane * 2] = make_float2(acc0, acc1);
}

extern "C" void kernel_launch(void* const* d_in, const int* in_sizes, int n_in,
                              void* d_out, int out_size, void* d_ws, size_t ws_size,
                              hipStream_t stream) {
    const float* x    = (const float*)d_in[0];
    const int*   edge = (const int*)d_in[1];   // JAX no-x64: int64 -> int32
    const float* W    = (const float*)d_in[2];
    const float* a    = (const float*)d_in[3];
    float* out = (float*)d_out;

    const int n = in_sizes[0] / D_IN;
    const int E = in_sizes[1] / 2;
    const int* src = edge;
    const int* dst = edge + E;

    // workspace layout (16B-aligned chunks)
    char* p = (char*)d_ws;
    unsigned short* hb  = (unsigned short*)p; p += (size_t)n * D_OUT * sizeof(unsigned short);
    unsigned short* WTb = (unsigned short*)p; p += (size_t)D_OUT * D_IN * sizeof(unsigned short);
    float* f_src   = (float*)p;  p += (size_t)n * sizeof(float);
    float* f_dst   = (float*)p;  p += (size_t)n * sizeof(float);
    int*   counts  = (int*)p;    p += (size_t)n * sizeof(int);
    int*   cursor  = (int*)p;    p += (size_t)n * sizeof(int);
    int*   csr_dst = (int*)p;    p += (size_t)E * sizeof(int);
    int*   row_ptr = (int*)p;    p += (size_t)(n + 1) * sizeof(int);
    int*   block_sums = (int*)p; p += 64 * sizeof(int);

    const int gemm_blocks = (n + 127) / 128;
    const int scan_blocks = (n + SCAN_CHUNK - 1) / SCAN_CHUNK;

    k_wt<<<D_OUT, 256, 0, stream>>>(W, WTb);
    k_gemm<<<gemm_blocks, 256, 0, stream>>>(x, WTb, hb, n);
    k_f<<<(n + 3) / 4, 256, 0, stream>>>(hb, a, f_src, f_dst, n);

    hipMemsetAsync(counts, 0, (size_t)n * sizeof(int), stream);
    k_hist<<<1280, 256, 0, stream>>>(src, counts, E);
    k_scan1<<<scan_blocks, 256, 0, stream>>>(counts, block_sums, n);
    k_scan2<<<scan_blocks, 256, 0, stream>>>(counts, block_sums, row_ptr, cursor, n);
    k_fill<<<1280, 256, 0, stream>>>(src, dst, cursor, csr_dst, E);

    k_agg<<<(n + 3) / 4, 256, 0, stream>>>(hb, f_src, f_dst, row_ptr, csr_dst, out, n, E);
}

// Round 3
// 347.565 us; speedup vs baseline: 1.4516x; 1.2545x over previous
//
#include <hip/hip_runtime.h>

#define D_IN 256
#define D_OUT 128
#define ALPHA 0.2f
#define SCAN_CHUNK 2048

typedef __attribute__((ext_vector_type(8))) short bf16x8;
typedef __attribute__((ext_vector_type(4))) float f32x4;

__device__ inline unsigned short f2bf(float f) {
    unsigned int u = __float_as_uint(f);
    return (unsigned short)((u + 0x7FFFu + ((u >> 16) & 1u)) >> 16);
}
__device__ inline float bf2f(unsigned short u) {
    return __uint_as_float(((unsigned int)u) << 16);
}

// ---------------- x fp32 -> xb bf16 (vectorized) ----------------
__global__ __launch_bounds__(256) void k_xb(const float* __restrict__ x,
                                            unsigned short* __restrict__ xb,
                                            size_t total8) {
    for (size_t i = (size_t)blockIdx.x * blockDim.x + threadIdx.x; i < total8;
         i += (size_t)gridDim.x * blockDim.x) {
        float4 a = ((const float4*)x)[2 * i];
        float4 b = ((const float4*)x)[2 * i + 1];
        bf16x8 v;
        v[0] = (short)f2bf(a.x); v[1] = (short)f2bf(a.y);
        v[2] = (short)f2bf(a.z); v[3] = (short)f2bf(a.w);
        v[4] = (short)f2bf(b.x); v[5] = (short)f2bf(b.y);
        v[6] = (short)f2bf(b.z); v[7] = (short)f2bf(b.w);
        ((bf16x8*)xb)[i] = v;
    }
}

// ---------------- W [256][128] fp32 -> WTb [128][256] bf16 (transposed) ----------------
__global__ __launch_bounds__(256) void k_wt(const float* __restrict__ W,
                                            unsigned short* __restrict__ WTb) {
    const int ncol = blockIdx.x;     // 0..127
    const int k = threadIdx.x;       // 0..255
    WTb[(size_t)ncol * 256 + k] = f2bf(W[(size_t)k * 128 + ncol]);
}

// ---------------- GEMM: hb = xb @ W, MFMA 16x16x32, no LDS, bf16 in ----------------
__global__ __launch_bounds__(256) void k_gemm(const unsigned short* __restrict__ xb,
                                              const unsigned short* __restrict__ WTb,
                                              unsigned short* __restrict__ hb, int n) {
    const int t = threadIdx.x;
    const int l = t & 63;
    const int w = t >> 6;
    const int wr = w >> 1, wc = w & 1;
    const int row0 = blockIdx.x * 128 + wr * 64;
    const int col0 = wc * 64;
    const int lr = l & 15;
    const int lk8 = (l >> 4) * 8;

    f32x4 acc[4][4] = {};

    const unsigned short* ap[4];
    #pragma unroll
    for (int mi = 0; mi < 4; ++mi) {
        int r = row0 + mi * 16 + lr;
        if (r > n - 1) r = n - 1;
        ap[mi] = xb + (size_t)r * D_IN + lk8;
    }
    const unsigned short* bp[4];
    #pragma unroll
    for (int ni = 0; ni < 4; ++ni)
        bp[ni] = WTb + (size_t)(col0 + ni * 16 + lr) * 256 + lk8;

    #pragma unroll
    for (int k0 = 0; k0 < D_IN; k0 += 32) {
        bf16x8 af[4], bfr[4];
        #pragma unroll
        for (int mi = 0; mi < 4; ++mi) af[mi]  = *(const bf16x8*)(ap[mi] + k0);
        #pragma unroll
        for (int ni = 0; ni < 4; ++ni) bfr[ni] = *(const bf16x8*)(bp[ni] + k0);
        #pragma unroll
        for (int mi = 0; mi < 4; ++mi)
            #pragma unroll
            for (int ni = 0; ni < 4; ++ni)
                acc[mi][ni] = __builtin_amdgcn_mfma_f32_16x16x32_bf16(
                    af[mi], bfr[ni], acc[mi][ni], 0, 0, 0);
    }

    const int rq = (l >> 4) * 4;
    #pragma unroll
    for (int mi = 0; mi < 4; ++mi) {
        #pragma unroll
        for (int q = 0; q < 4; ++q) {
            int r = row0 + mi * 16 + rq + q;
            if (r < n) {
                #pragma unroll
                for (int ni = 0; ni < 4; ++ni)
                    hb[(size_t)r * D_OUT + col0 + ni * 16 + lr] =
                        f2bf(acc[mi][ni][q]);
            }
        }
    }
}

// ---------------- f_src / f_dst ----------------
__global__ __launch_bounds__(256) void k_f(const unsigned short* __restrict__ hb,
                                           const float* __restrict__ a,
                                           float* __restrict__ f_src,
                                           float* __restrict__ f_dst, int n) {
    const int node = blockIdx.x * 4 + (threadIdx.x >> 6);
    const int lane = threadIdx.x & 63;
    if (node >= n) return;
    ushort2 hv = *(const ushort2*)&hb[(size_t)node * D_OUT + lane * 2];
    float h0 = bf2f(hv.x), h1 = bf2f(hv.y);
    float fs = h0 * a[lane * 2]         + h1 * a[lane * 2 + 1];
    float fd = h0 * a[D_OUT + lane * 2] + h1 * a[D_OUT + lane * 2 + 1];
    #pragma unroll
    for (int off = 32; off > 0; off >>= 1) {
        fs += __shfl_down(fs, off);
        fd += __shfl_down(fd, off);
    }
    if (lane == 0) {
        f_src[node] = fs;
        f_dst[node] = fd;
    }
}

// ---------------- histogram ----------------
__global__ __launch_bounds__(256) void k_hist(const int* __restrict__ src,
                                              int* __restrict__ counts, int E) {
    for (int e = blockIdx.x * blockDim.x + threadIdx.x; e < E;
         e += gridDim.x * blockDim.x) {
        atomicAdd(&counts[src[e]], 1);
    }
}

// ---------------- scan pass 1 ----------------
__global__ __launch_bounds__(256) void k_scan1(const int* __restrict__ counts,
                                               int* __restrict__ block_sums, int n) {
    const int t = threadIdx.x;
    const int base = blockIdx.x * SCAN_CHUNK;
    int s = 0;
    for (int i = t; i < SCAN_CHUNK; i += 256) {
        int idx = base + i;
        if (idx < n) s += counts[idx];
    }
    #pragma unroll
    for (int off = 32; off > 0; off >>= 1) s += __shfl_down(s, off);
    __shared__ int wsums[4];
    if ((t & 63) == 0) wsums[t >> 6] = s;
    __syncthreads();
    if (t == 0) block_sums[blockIdx.x] = wsums[0] + wsums[1] + wsums[2] + wsums[3];
}

// ---------------- scan pass 2 ----------------
__global__ __launch_bounds__(256) void k_scan2(const int* __restrict__ counts,
                                               const int* __restrict__ block_sums,
                                               int* __restrict__ row_ptr,
                                               int* __restrict__ cursor, int n) {
    const int t = threadIdx.x;
    const int b = blockIdx.x;
    const int base = b * SCAN_CHUNK;

    int po = 0;
    for (int i = t; i < b; i += 256) po += block_sums[i];
    #pragma unroll
    for (int off = 32; off > 0; off >>= 1) po += __shfl_down(po, off);
    __shared__ int wsums[4];
    __shared__ int sOff;
    if ((t & 63) == 0) wsums[t >> 6] = po;
    __syncthreads();
    if (t == 0) sOff = wsums[0] + wsums[1] + wsums[2] + wsums[3];
    __syncthreads();

    const int idx0 = base + t * 8;
    int v[8];
    int total = 0;
    #pragma unroll
    for (int j = 0; j < 8; ++j) {
        int idx = idx0 + j;
        v[j] = (idx < n) ? counts[idx] : 0;
        total += v[j];
    }
    __shared__ int sc[256];
    sc[t] = total;
    __syncthreads();
    #pragma unroll
    for (int off = 1; off < 256; off <<= 1) {
        int add = (t >= off) ? sc[t - off] : 0;
        __syncthreads();
        sc[t] += add;
        __syncthreads();
    }
    int gbase = sOff + sc[t] - total;
    int run = 0;
    #pragma unroll
    for (int j = 0; j < 8; ++j) {
        int idx = idx0 + j;
        if (idx < n) {
            row_ptr[idx] = gbase + run;
            cursor[idx]  = gbase + run;
        }
        run += v[j];
    }
}

// ---------------- CSR fill ----------------
__global__ __launch_bounds__(256) void k_fill(const int* __restrict__ src,
                                              const int* __restrict__ dst,
                                              int* __restrict__ cursor,
                                              int* __restrict__ csr_dst, int E) {
    for (int e = blockIdx.x * blockDim.x + threadIdx.x; e < E;
         e += gridDim.x * blockDim.x) {
        int s = src[e];
        int p = atomicAdd(&cursor[s], 1);
        csr_dst[p] = dst[e];
    }
}

// ---------------- aggregation: wave/node, parallel weights + staged indices ----------------
__global__ __launch_bounds__(256) void k_agg(const unsigned short* __restrict__ hb,
                                             const float* __restrict__ f_src,
                                             const float* __restrict__ f_dst,
                                             const int* __restrict__ row_ptr,
                                             const int* __restrict__ csr_dst,
                                             float* __restrict__ out, int n, int E) {
    __shared__ int2 stage[4][64];
    const int wid = threadIdx.x >> 6;
    const int node = blockIdx.x * 4 + wid;
    if (node >= n) return;
    const int lane = threadIdx.x & 63;
    const int beg = row_ptr[node];
    const int end = (node == n - 1) ? E : row_ptr[node + 1];
    const float fs = f_src[node];

    float acc0 = 0.f, acc1 = 0.f, rowsum = 0.f;

    for (int c = beg; c < end; c += 64) {
        const int j = c + lane;
        int d = 0;
        float wgt = 0.f;
        if (j < end) {
            d = csr_dst[j];
            float tmp = fs + f_dst[d];
            float lr = (tmp > 0.f) ? tmp : ALPHA * tmp;
            wgt = __expf(-lr);
        }
        rowsum += wgt;
        stage[wid][lane] = make_int2(d, __float_as_int(wgt));
        const int cnt = min(64, end - c);
        #pragma unroll 4
        for (int jj = 0; jj < cnt; ++jj) {
            int2 dw = stage[wid][jj];           // uniform address -> broadcast
            float wj = __int_as_float(dw.y);
            ushort2 hv = *(const ushort2*)&hb[(size_t)dw.x * D_OUT + lane * 2];
            acc0 = fmaf(wj, bf2f(hv.x), acc0);
            acc1 = fmaf(wj, bf2f(hv.y), acc1);
        }
    }

    #pragma unroll
    for (int off = 32; off > 0; off >>= 1) rowsum += __shfl_xor(rowsum, off);

    float inv = 1.f / rowsum;
    acc0 *= inv;
    acc1 *= inv;
    acc0 = (acc0 > 0.f) ? acc0 : (__expf(acc0) - 1.f);
    acc1 = (acc1 > 0.f) ? acc1 : (__expf(acc1) - 1.f);
    *(float2*)&out[(size_t)node * D_OUT + lane * 2] = make_float2(acc0, acc1);
}

extern "C" void kernel_launch(void* const* d_in, const int* in_sizes, int n_in,
                              void* d_out, int out_size, void* d_ws, size_t ws_size,
                              hipStream_t stream) {
    const float* x    = (const float*)d_in[0];
    const int*   edge = (const int*)d_in[1];   // JAX no-x64: int64 -> int32
    const float* W    = (const float*)d_in[2];
    const float* a    = (const float*)d_in[3];
    float* out = (float*)d_out;

    const int n = in_sizes[0] / D_IN;
    const int E = in_sizes[1] / 2;
    const int* src = edge;
    const int* dst = edge + E;

    char* p = (char*)d_ws;
    unsigned short* hb  = (unsigned short*)p; p += (size_t)n * D_OUT * sizeof(unsigned short);
    unsigned short* xb  = (unsigned short*)p; p += (size_t)n * D_IN * sizeof(unsigned short);
    unsigned short* WTb = (unsigned short*)p; p += (size_t)D_OUT * D_IN * sizeof(unsigned short);
    float* f_src   = (float*)p;  p += (size_t)n * sizeof(float);
    float* f_dst   = (float*)p;  p += (size_t)n * sizeof(float);
    int*   counts  = (int*)p;    p += (size_t)n * sizeof(int);
    int*   cursor  = (int*)p;    p += (size_t)n * sizeof(int);
    int*   csr_dst = (int*)p;    p += (size_t)E * sizeof(int);
    int*   row_ptr = (int*)p;    p += (size_t)(n + 1) * sizeof(int);
    int*   block_sums = (int*)p; p += 64 * sizeof(int);

    const int gemm_blocks = (n + 127) / 128;
    const int scan_blocks = (n + SCAN_CHUNK - 1) / SCAN_CHUNK;
    const size_t total8 = (size_t)n * D_IN / 8;

    k_xb<<<2048, 256, 0, stream>>>(x, xb, total8);
    k_wt<<<D_OUT, 256, 0, stream>>>(W, WTb);
    k_gemm<<<gemm_blocks, 256, 0, stream>>>(xb, WTb, hb, n);
    k_f<<<(n + 3) / 4, 256, 0, stream>>>(hb, a, f_src, f_dst, n);

    hipMemsetAsync(counts, 0, (size_t)n * sizeof(int), stream);
    k_hist<<<1280, 256, 0, stream>>>(src, counts, E);
    k_scan1<<<scan_blocks, 256, 0, stream>>>(counts, block_sums, n);
    k_scan2<<<scan_blocks, 256, 0, stream>>>(counts, block_sums, row_ptr, cursor, n);
    k_fill<<<1280, 256, 0, stream>>>(src, dst, cursor, csr_dst, E);

    k_agg<<<(n + 3) / 4, 256, 0, stream>>>(hb, f_src, f_dst, row_ptr, csr_dst, out, n, E);
}